// Round 13
// baseline (155.798 us; speedup 1.0000x reference)
//
#include <hip/hip_runtime.h>
#include <hip/hip_bf16.h>
#include <hip/hip_fp16.h>

#define CHUNK 4096       // edges per scatter block
#define BCAP 64          // bucket capacity per node (deg ~ Poisson(16))
#define BIN_CAP 6144     // pairs capacity per 256-node coarse bin
#define NSRCP 4          // source partitions (KV slice 3.2MB < 4MB L2)

typedef _Float16 half8 __attribute__((ext_vector_type(8)));
typedef _Float16 half2v __attribute__((ext_vector_type(2)));
typedef float floatx4 __attribute__((ext_vector_type(4)));

__device__ __forceinline__ float2 h2f(int u)
{
    __half2 h = *reinterpret_cast<__half2*>(&u);
    return __half22float2(h);
}

__device__ __forceinline__ half2v as_h2(int u)
{
    union { int i; half2v h; } c; c.i = u; return c.h;
}

__device__ __forceinline__ int pack_h2(float a, float b)
{
    union { int i; half2v h; } c;
    c.h = (half2v){(_Float16)a, (_Float16)b};
    return c.i;
}

// ---------------------------------------------------------------------------
// MFMA GEMM layer 1: [Q|K|V|S] = X[n][64] @ W + b, per 64-node tile.
// Block 0 also inits bincur. q pre-scaled; KV packed [k01][k23][v01][v23].
// ---------------------------------------------------------------------------
__global__ __launch_bounds__(256) void gemm1(
    const float* __restrict__ X, int n,
    const float* __restrict__ W0, const float* __restrict__ W1,
    const float* __restrict__ W2, const float* __restrict__ W3,
    const float* __restrict__ B0, const float* __restrict__ B1,
    const float* __restrict__ B2, const float* __restrict__ B3,
    __half* __restrict__ Q, __half* __restrict__ S, __half* __restrict__ KV,
    int* __restrict__ bincur, int nbins)
{
    constexpr int HD = 64;
    constexpr int NTW = 4;
    const float qscale = 0.17677669529663687f;  // 1/sqrt(32)

    __shared__ _Float16 A_lds[64][72];
    __shared__ _Float16 B_lds[4 * HD][72];

    const int tid = threadIdx.x;
    const int n0 = blockIdx.x * 64;

    if (blockIdx.x == 0 && tid < nbins) bincur[tid] = tid * BIN_CAP;

    {
        const int row = tid >> 2;
        const int cb  = (tid & 3) * 16;
        const int gnode = n0 + row;
        if (gnode < n) {
            const float4* xg = reinterpret_cast<const float4*>(X + (size_t)gnode * 64 + cb);
#pragma unroll
            for (int t = 0; t < 4; ++t) {
                const float4 v = xg[t];
                A_lds[row][cb + 4 * t + 0] = (_Float16)v.x;
                A_lds[row][cb + 4 * t + 1] = (_Float16)v.y;
                A_lds[row][cb + 4 * t + 2] = (_Float16)v.z;
                A_lds[row][cb + 4 * t + 3] = (_Float16)v.w;
            }
        } else {
            const int4 z = {0, 0, 0, 0};
            *reinterpret_cast<int4*>(&A_lds[row][cb])     = z;
            *reinterpret_cast<int4*>(&A_lds[row][cb + 8]) = z;
        }
    }

    {
        const float* Ws[4] = {W0, W1, W2, W3};
#pragma unroll
        for (int m = 0; m < 4; ++m) {
            const float* W = Ws[m];
            for (int idx = tid; idx < 64 * HD; idx += 256) {
                const int k = idx / HD;
                const int jj = idx - k * HD;
                B_lds[m * HD + jj][k] = (_Float16)W[idx];
            }
        }
    }

    __syncthreads();

    const int w = tid >> 6;
    const int lane = tid & 63;
    const int lr = lane & 15;
    const int lk = (lane >> 4) * 8;

    half8 a[4][2];
#pragma unroll
    for (int mt = 0; mt < 4; ++mt)
#pragma unroll
        for (int ks = 0; ks < 2; ++ks)
            a[mt][ks] = *reinterpret_cast<const half8*>(&A_lds[mt * 16 + lr][ks * 32 + lk]);

    half8 b[NTW][2];
#pragma unroll
    for (int nt = 0; nt < NTW; ++nt)
#pragma unroll
        for (int ks = 0; ks < 2; ++ks)
            b[nt][ks] = *reinterpret_cast<const half8*>(&B_lds[w * HD + nt * 16 + lr][ks * 32 + lk]);

    floatx4 acc[4][NTW];
#pragma unroll
    for (int mt = 0; mt < 4; ++mt)
#pragma unroll
        for (int nt = 0; nt < NTW; ++nt)
            acc[mt][nt] = (floatx4){0.f, 0.f, 0.f, 0.f};

#pragma unroll
    for (int mt = 0; mt < 4; ++mt)
#pragma unroll
        for (int nt = 0; nt < NTW; ++nt) {
            acc[mt][nt] = __builtin_amdgcn_mfma_f32_16x16x32_f16(a[mt][0], b[nt][0], acc[mt][nt], 0, 0, 0);
            acc[mt][nt] = __builtin_amdgcn_mfma_f32_16x16x32_f16(a[mt][1], b[nt][1], acc[mt][nt], 0, 0, 0);
        }

    const float* Bv = (w == 0) ? B0 : (w == 1) ? B1 : (w == 2) ? B2 : B3;
    float bias[NTW];
#pragma unroll
    for (int nt = 0; nt < NTW; ++nt) bias[nt] = Bv[nt * 16 + lr];

#pragma unroll
    for (int mt = 0; mt < 4; ++mt) {
#pragma unroll
        for (int nt = 0; nt < NTW; ++nt) {
            const int jj = nt * 16 + lr;
#pragma unroll
            for (int r = 0; r < 4; ++r) {
                const int node = n0 + mt * 16 + (lane >> 4) * 4 + r;
                if (node < n) {
                    const float val = acc[mt][nt][r] + bias[nt];
                    if (w == 0)      Q[(size_t)node * HD + jj] = __float2half(val * qscale);
                    else if (w == 3) S[(size_t)node * HD + jj] = __float2half(val);
                    else             KV[(size_t)node * 2 * HD + (jj >> 2) * 8 + (w - 1) * 4 + (jj & 3)]
                                         = __float2half(val);
                }
            }
        }
    }
}

// ---------------------------------------------------------------------------
// Adjacency build: fixed-capacity coarse bins, block-claimed ranges.
// ---------------------------------------------------------------------------
__global__ __launch_bounds__(256) void scatter_fused(
    const int* __restrict__ src, const int* __restrict__ dst,
    int* __restrict__ bincur, int2* __restrict__ pairs,
    int e, int nbins)
{
    __shared__ int lh[256];
    __shared__ int lbase[256];
    const int b = blockIdx.x;
    const int tid = threadIdx.x;
    if (tid < 256) lh[tid] = 0;
    __syncthreads();

    const int base = b * CHUNK;
    const int end = min(base + CHUNK, e);

    for (int i = base + tid * 4; i < end; i += 1024) {
        if (i + 4 <= end) {
            const int4 d4 = *reinterpret_cast<const int4*>(dst + i);
            atomicAdd(&lh[d4.x >> 8], 1);
            atomicAdd(&lh[d4.y >> 8], 1);
            atomicAdd(&lh[d4.z >> 8], 1);
            atomicAdd(&lh[d4.w >> 8], 1);
        } else {
            for (int jj = i; jj < end; ++jj) atomicAdd(&lh[dst[jj] >> 8], 1);
        }
    }
    __syncthreads();

    int mycnt = 0;
    if (tid < nbins) {
        mycnt = lh[tid];
        if (mycnt > 0) lbase[tid] = atomicAdd(&bincur[tid], mycnt);
    }
    __syncthreads();
    if (tid < 256) lh[tid] = 0;
    __syncthreads();

    for (int i = base + tid * 4; i < end; i += 1024) {
        if (i + 4 <= end) {
            const int4 d4 = *reinterpret_cast<const int4*>(dst + i);
            const int4 s4 = *reinterpret_cast<const int4*>(src + i);
            int bin, off;
            bin = d4.x >> 8; off = atomicAdd(&lh[bin], 1); pairs[lbase[bin] + off] = make_int2(d4.x, s4.x);
            bin = d4.y >> 8; off = atomicAdd(&lh[bin], 1); pairs[lbase[bin] + off] = make_int2(d4.y, s4.y);
            bin = d4.z >> 8; off = atomicAdd(&lh[bin], 1); pairs[lbase[bin] + off] = make_int2(d4.z, s4.z);
            bin = d4.w >> 8; off = atomicAdd(&lh[bin], 1); pairs[lbase[bin] + off] = make_int2(d4.w, s4.w);
        } else {
            for (int jj = i; jj < end; ++jj) {
                const int d = dst[jj];
                const int bin = d >> 8;
                const int off = atomicAdd(&lh[bin], 1);
                pairs[lbase[bin] + off] = make_int2(d, src[jj]);
            }
        }
    }
}

// ---------------------------------------------------------------------------
// fine_bucket: per 256-node bin, bucket each node's srcs ORDERED BY SOURCE
// PARTITION (4 parts); emits cnt (total) and cnt4 (per-part counts).
// ---------------------------------------------------------------------------
__global__ __launch_bounds__(512) void fine_bucket(
    const int2* __restrict__ pairs, const int* __restrict__ bincur,
    int* __restrict__ cnt, int4* __restrict__ cnt4, int* __restrict__ bucket,
    int n, int psize)
{
    __shared__ int cur[1024];   // [local node][part]
    const int g = blockIdx.x;
    const int tid = threadIdx.x;
    const int n0 = g << 8;
    cur[tid] = 0; cur[tid + 512] = 0;
    __syncthreads();

    const int e0 = g * BIN_CAP;
    const int e1 = bincur[g];

    for (int i = e0 + tid; i < e1; i += 512) {
        const int2 pr = pairs[i];
        const int s = pr.y;
        const int part = (s >= psize) + (s >= 2 * psize) + (s >= 3 * psize);
        atomicAdd(&cur[(pr.x - n0) * 4 + part], 1);
    }
    __syncthreads();

    if (tid < 256) {
        const int c0 = cur[tid * 4], c1 = cur[tid * 4 + 1];
        const int c2 = cur[tid * 4 + 2], c3 = cur[tid * 4 + 3];
        const int node = n0 + tid;
        if (node < n) {
            cnt[node] = c0 + c1 + c2 + c3;
            cnt4[node] = make_int4(c0, c1, c2, c3);
        }
        cur[tid * 4]     = 0;
        cur[tid * 4 + 1] = c0;
        cur[tid * 4 + 2] = c0 + c1;
        cur[tid * 4 + 3] = c0 + c1 + c2;
    }
    __syncthreads();

    for (int i = e0 + tid; i < e1; i += 512) {
        const int2 pr = pairs[i];
        const int s = pr.y;
        const int part = (s >= psize) + (s >= 2 * psize) + (s >= 3 * psize);
        const int slot = atomicAdd(&cur[(pr.x - n0) * 4 + part], 1);
        if (slot < BCAP) bucket[(size_t)pr.x * BCAP + slot] = s;
    }
}

// ---------------------------------------------------------------------------
// Split-K partial attention (layer 1). Block = 256 thr / 4 waves; each wave
// handles one (node, part). XCD-pinned: part = (blockIdx&7)>>1 so partition p
// runs on XCDs {2p,2p+1} -> per-XCD KV working set 3.2MB (L2-resident).
// Writes pacc fp16[node][4][64] and pden f32[node][4][2].
// ---------------------------------------------------------------------------
__global__ __launch_bounds__(256) void attn1_part(
    const __half* __restrict__ Q1, const int4* __restrict__ KV1,
    const int4* __restrict__ cnt4, const int* __restrict__ bucket,
    __half* __restrict__ pacc, float* __restrict__ pden, int n)
{
    const int b = blockIdx.x;
    const int p = (b & 7) >> 1;
    const int chunk = ((b >> 3) << 1) + (b & 1);
    const int node = chunk * 4 + (threadIdx.x >> 6);
    const int lane = threadIdx.x & 63;
    const int slot = lane >> 4;
    const int j = lane & 15;
    if (node >= n) return;

    const int4 c4 = cnt4[node];
    int base, dp;
    if (p == 0)      { base = 0;                   dp = c4.x; }
    else if (p == 1) { base = c4.x;                dp = c4.y; }
    else if (p == 2) { base = c4.x + c4.y;         dp = c4.z; }
    else             { base = c4.x + c4.y + c4.z;  dp = c4.w; }
    base = min(base, BCAP);
    dp = min(dp, BCAP - base);

    float acc0 = 0.f, acc1 = 0.f, acc2 = 0.f, acc3 = 0.f, den = 0.f;

    if (dp > 0) {
        const int2 qi = reinterpret_cast<const int2*>(Q1 + (size_t)node * 64)[j];
        const half2v q01 = as_h2(qi.x), q23 = as_h2(qi.y);
        const int* blist = bucket + (size_t)node * BCAP + base;
        const int nit = (dp + 3) >> 2;
        for (int it = 0; it < nit; ++it) {
            const int en = (it << 2) + slot;
            const bool v = en < dp;
            const int s = v ? blist[en] : 0;
            const int4 kv = KV1[(size_t)s * 16 + j];
            float pp = __builtin_amdgcn_fdot2(as_h2(kv.x), q01,
                       __builtin_amdgcn_fdot2(as_h2(kv.y), q23, 0.f, false), false);
            pp += __shfl_xor(pp, 1);
            pp += __shfl_xor(pp, 2);
            pp += __shfl_xor(pp, 4);
            const float ex = v ? __expf(pp) : 0.f;
            const float2 v01 = h2f(kv.z), v23 = h2f(kv.w);
            den += ex;
            acc0 = fmaf(ex, v01.x, acc0);
            acc1 = fmaf(ex, v01.y, acc1);
            acc2 = fmaf(ex, v23.x, acc2);
            acc3 = fmaf(ex, v23.y, acc3);
        }
    }

    acc0 += __shfl_xor(acc0, 16); acc0 += __shfl_xor(acc0, 32);
    acc1 += __shfl_xor(acc1, 16); acc1 += __shfl_xor(acc1, 32);
    acc2 += __shfl_xor(acc2, 16); acc2 += __shfl_xor(acc2, 32);
    acc3 += __shfl_xor(acc3, 16); acc3 += __shfl_xor(acc3, 32);
    den  += __shfl_xor(den, 16);  den  += __shfl_xor(den, 32);

    if (lane < 16) {
        int2 ov = {pack_h2(acc0, acc1), pack_h2(acc2, acc3)};
        reinterpret_cast<int2*>(pacc)[((size_t)node * 4 + p) * 16 + j] = ov;
    }
    if (lane == 0) pden[(size_t)node * 8 + p * 2]     = den;
    if (lane == 8) pden[(size_t)node * 8 + p * 2 + 1] = den;
}

// ---------------------------------------------------------------------------
// Combine partials (layer-1 epilogue: sum parts, /den, +skip, relu) + gemm2.
// Block = 1024 thr / 16 waves, 64 nodes.
// ---------------------------------------------------------------------------
__global__ __launch_bounds__(1024, 8) void combine_gemm2(
    const __half* __restrict__ pacc, const float* __restrict__ pden,
    const __half* __restrict__ S1,
    const float* __restrict__ W0, const float* __restrict__ W1,
    const float* __restrict__ W2, const float* __restrict__ W3,
    const float* __restrict__ B0, const float* __restrict__ B1,
    const float* __restrict__ B2, const float* __restrict__ B3,
    __half* __restrict__ Q2, __half* __restrict__ S2, __half* __restrict__ KV2,
    int n)
{
    const float qscale = 0.17677669529663687f;  // 1/sqrt(32)

    __shared__ _Float16 A_lds[64][72];
    __shared__ _Float16 B_lds[128][72];

    const int tid = threadIdx.x;
    const int n0 = blockIdx.x * 64;
    const int w = tid >> 6;
    const int lane = tid & 63;
    const int j = lane & 15;

    {
        const float* Ws[4] = {W0, W1, W2, W3};
#pragma unroll
        for (int m = 0; m < 4; ++m) {
            const float* W = Ws[m];
            for (int idx = tid; idx < 64 * 32; idx += 1024) {
                const int k = idx >> 5;
                const int jj = idx & 31;
                B_lds[m * 32 + jj][k] = (_Float16)W[idx];
            }
        }
    }

    // ---- phase 1: combine partials into h tile ----
    for (int nd = 0; nd < 4; ++nd) {
        const int node = n0 + w * 4 + nd;
        if (lane < 16) {
            float o0 = 0.f, o1 = 0.f, o2 = 0.f, o3 = 0.f;
            if (node < n) {
                float a0 = 0.f, a1 = 0.f, a2 = 0.f, a3 = 0.f, den = 0.f;
#pragma unroll
                for (int p = 0; p < 4; ++p) {
                    const int2 v = reinterpret_cast<const int2*>(pacc)[((size_t)node * 4 + p) * 16 + j];
                    const float2 x01 = h2f(v.x), x23 = h2f(v.y);
                    a0 += x01.x; a1 += x01.y; a2 += x23.x; a3 += x23.y;
                    den += pden[(size_t)node * 8 + p * 2 + (j >> 3)];
                }
                const float inv = (den > 0.f) ? (1.f / den) : 0.f;
                const int2 si = reinterpret_cast<const int2*>(S1 + (size_t)node * 64)[j];
                const float2 s01 = h2f(si.x), s23 = h2f(si.y);
                o0 = fmaxf(fmaf(a0, inv, s01.x), 0.f);
                o1 = fmaxf(fmaf(a1, inv, s01.y), 0.f);
                o2 = fmaxf(fmaf(a2, inv, s23.x), 0.f);
                o3 = fmaxf(fmaf(a3, inv, s23.y), 0.f);
            }
            int2 ov = {pack_h2(o0, o1), pack_h2(o2, o3)};
            *reinterpret_cast<int2*>(&A_lds[w * 4 + nd][4 * j]) = ov;
        }
    }

    __syncthreads();

    // ---- phase 2: gemm2 (32 16x16 tiles, 2 per wave) ----
    const int lr = lane & 15;
    const int lk = (lane >> 4) * 8;

#pragma unroll
    for (int tt = 0; tt < 2; ++tt) {
        const int t = w + tt * 16;
        const int mt = t >> 3;
        const int ntg = t & 7;
        const int m = ntg >> 1;
        const int nt = ntg & 1;

        const half8 af0 = *reinterpret_cast<const half8*>(&A_lds[mt * 16 + lr][lk]);
        const half8 af1 = *reinterpret_cast<const half8*>(&A_lds[mt * 16 + lr][32 + lk]);
        const half8 bf0 = *reinterpret_cast<const half8*>(&B_lds[ntg * 16 + lr][lk]);
        const half8 bf1 = *reinterpret_cast<const half8*>(&B_lds[ntg * 16 + lr][32 + lk]);

        floatx4 acc = (floatx4){0.f, 0.f, 0.f, 0.f};
        acc = __builtin_amdgcn_mfma_f32_16x16x32_f16(af0, bf0, acc, 0, 0, 0);
        acc = __builtin_amdgcn_mfma_f32_16x16x32_f16(af1, bf1, acc, 0, 0, 0);

        const float* Bv = (m == 0) ? B0 : (m == 1) ? B1 : (m == 2) ? B2 : B3;
        const int jj = nt * 16 + lr;
        const float bias = Bv[jj];

#pragma unroll
        for (int r = 0; r < 4; ++r) {
            const int node = n0 + mt * 16 + (lane >> 4) * 4 + r;
            if (node < n) {
                const float val = acc[r] + bias;
                if (m == 0)      Q2[(size_t)node * 32 + jj] = __float2half(val * qscale);
                else if (m == 3) S2[(size_t)node * 32 + jj] = __float2half(val);
                else             KV2[(size_t)node * 64 + (jj >> 2) * 8 + (m - 1) * 4 + (jj & 3)]
                                     = __float2half(val);
            }
        }
    }
}

// ---------------------------------------------------------------------------
// Attention layer 2: heads=1, d=32. One wave per node, 8 edges/iter,
// 2-deep pipeline. Output f32 (d_out).
// ---------------------------------------------------------------------------
__global__ void attn_h1(const __half* __restrict__ Qh, const __half* __restrict__ Sh,
                        const int4* __restrict__ KVi, const int* __restrict__ cnt,
                        const int* __restrict__ bucket, float4* __restrict__ outf4, int n)
{
    const int wid = (blockIdx.x * blockDim.x + threadIdx.x) >> 6;
    if (wid >= n) return;
    const int lane = threadIdx.x & 63;
    const int slot = lane >> 3;
    const int j = lane & 7;

    const int2 qi = reinterpret_cast<const int2*>(Qh + (size_t)wid * 32)[j];
    const half2v q01 = as_h2(qi.x), q23 = as_h2(qi.y);

    const int deg = min(cnt[wid], BCAP);
    const int* blist = bucket + (size_t)wid * BCAP;

    float acc0 = 0.f, acc1 = 0.f, acc2 = 0.f, acc3 = 0.f, den = 0.f;

    if (deg > 0) {
        const int nit = (deg + 7) >> 3;

        int e = slot;
        bool vc = e < deg;
        int sc = vc ? blist[e] : 0;
        int4 kv = KVi[(size_t)sc * 8 + j];

        for (int it = 1; it < nit; ++it) {
            const int en = (it << 3) + slot;
            const bool vn = en < deg;
            const int sn = vn ? blist[en] : 0;
            const int4 kvn = KVi[(size_t)sn * 8 + j];

            float p = __builtin_amdgcn_fdot2(as_h2(kv.x), q01,
                      __builtin_amdgcn_fdot2(as_h2(kv.y), q23, 0.f, false), false);
            p += __shfl_xor(p, 1);
            p += __shfl_xor(p, 2);
            p += __shfl_xor(p, 4);
            const float ex = vc ? __expf(p) : 0.f;
            const float2 v01 = h2f(kv.z), v23 = h2f(kv.w);
            den += ex;
            acc0 = fmaf(ex, v01.x, acc0);
            acc1 = fmaf(ex, v01.y, acc1);
            acc2 = fmaf(ex, v23.x, acc2);
            acc3 = fmaf(ex, v23.y, acc3);

            kv = kvn; vc = vn;
        }
        {
            float p = __builtin_amdgcn_fdot2(as_h2(kv.x), q01,
                      __builtin_amdgcn_fdot2(as_h2(kv.y), q23, 0.f, false), false);
            p += __shfl_xor(p, 1);
            p += __shfl_xor(p, 2);
            p += __shfl_xor(p, 4);
            const float ex = vc ? __expf(p) : 0.f;
            const float2 v01 = h2f(kv.z), v23 = h2f(kv.w);
            den += ex;
            acc0 = fmaf(ex, v01.x, acc0);
            acc1 = fmaf(ex, v01.y, acc1);
            acc2 = fmaf(ex, v23.x, acc2);
            acc3 = fmaf(ex, v23.y, acc3);
        }
    }

    acc0 += __shfl_xor(acc0, 8); acc0 += __shfl_xor(acc0, 16); acc0 += __shfl_xor(acc0, 32);
    acc1 += __shfl_xor(acc1, 8); acc1 += __shfl_xor(acc1, 16); acc1 += __shfl_xor(acc1, 32);
    acc2 += __shfl_xor(acc2, 8); acc2 += __shfl_xor(acc2, 16); acc2 += __shfl_xor(acc2, 32);
    acc3 += __shfl_xor(acc3, 8); acc3 += __shfl_xor(acc3, 16); acc3 += __shfl_xor(acc3, 32);
    den  += __shfl_xor(den, 8);  den  += __shfl_xor(den, 16);  den  += __shfl_xor(den, 32);

    const float inv = (den > 0.f) ? (1.f / den) : 0.f;
    const int2 si = reinterpret_cast<const int2*>(Sh + (size_t)wid * 32)[j];
    const float2 s01 = h2f(si.x), s23 = h2f(si.y);
    float4 o;
    o.x = fmaf(acc0, inv, s01.x);
    o.y = fmaf(acc1, inv, s01.y);
    o.z = fmaf(acc2, inv, s23.x);
    o.w = fmaf(acc3, inv, s23.y);
    if (lane < 8) outf4[(size_t)wid * 8 + j] = o;
}

// ---------------------------------------------------------------------------
extern "C" void kernel_launch(void* const* d_in, const int* in_sizes, int n_in,
                              void* d_out, int out_size, void* d_ws, size_t ws_size,
                              hipStream_t stream)
{
    const float* x   = (const float*)d_in[0];
    const int* ei    = (const int*)d_in[1];
    const float* Wq1 = (const float*)d_in[2];  const float* bq1 = (const float*)d_in[3];
    const float* Wk1 = (const float*)d_in[4];  const float* bk1 = (const float*)d_in[5];
    const float* Wv1 = (const float*)d_in[6];  const float* bv1 = (const float*)d_in[7];
    const float* Ws1 = (const float*)d_in[8];  const float* bs1 = (const float*)d_in[9];
    const float* Wq2 = (const float*)d_in[10]; const float* bq2 = (const float*)d_in[11];
    const float* Wk2 = (const float*)d_in[12]; const float* bk2 = (const float*)d_in[13];
    const float* Wv2 = (const float*)d_in[14]; const float* bv2 = (const float*)d_in[15];
    const float* Ws2 = (const float*)d_in[16]; const float* bs2 = (const float*)d_in[17];

    const int n = in_sizes[0] / 64;   // 50000
    const int e = in_sizes[1] / 2;    // 800000
    const int* src = ei;
    const int* dst = ei + e;

    // workspace layout
    __half* q1   = (__half*)d_ws;                      // n*64
    __half* s1   = q1 + (size_t)n * 64;                // n*64
    __half* kv1  = s1 + (size_t)n * 64;                // n*128
    __half* q2   = kv1 + (size_t)n * 128;              // n*32
    __half* s2   = q2 + (size_t)n * 32;                // n*32
    __half* kv2  = s2 + (size_t)n * 32;                // n*64
    __half* pacc = kv2 + (size_t)n * 64;               // n*4*64
    float*  pden = (float*)(pacc + (size_t)n * 256);   // n*4*2
    int*  cnt    = (int*)(pden + (size_t)n * 8);       // n
    int4* cnt4   = (int4*)(cnt + n);                   // n
    int*  bucket = (int*)(cnt4 + n);                   // n*BCAP
    const int nbins = (n + 255) >> 8;                  // 196
    int2* pairs  = (int2*)(bucket + (size_t)n * BCAP); // nbins*BIN_CAP
    int*  bincur = (int*)(pairs + (size_t)nbins * BIN_CAP);  // nbins

    float* out = (float*)d_out;
    const int nblk  = (e + CHUNK - 1) / CHUNK;         // 196
    const int nb_gemm = (n + 63) / 64;
    const int psize = (n + NSRCP - 1) / NSRCP;         // 12500
    const int nchunks = (n + 3) / 4;                   // 12500
    const int nblk_att = ((NSRCP * nchunks + 7) / 8) * 8;

    // ---- layer-1 GEMM (also inits bincur) ----
    gemm1<<<nb_gemm, 256, 0, stream>>>(
        x, n, Wq1, Wk1, Wv1, Ws1, bq1, bk1, bv1, bs1, q1, s1, kv1,
        bincur, nbins);

    // ---- adjacency build ----
    scatter_fused<<<nblk, 256, 0, stream>>>(src, dst, bincur, pairs, e, nbins);
    fine_bucket<<<nbins, 512, 0, stream>>>(pairs, bincur, cnt, cnt4, bucket, n, psize);

    // ---- split-K layer-1 attention (XCD-pinned source partitions) ----
    attn1_part<<<nblk_att, 256, 0, stream>>>(
        q1, (const int4*)kv1, cnt4, bucket, pacc, pden, n);

    // ---- combine + layer-2 GEMM ----
    combine_gemm2<<<nb_gemm, 1024, 0, stream>>>(
        pacc, pden, s1,
        Wq2, Wk2, Wv2, Ws2, bq2, bk2, bv2, bs2,
        q2, s2, kv2, n);

    // ---- layer-2 attention ----
    attn_h1<<<(n + 3) / 4, 256, 0, stream>>>(
        q2, s2, (const int4*)kv2, cnt, bucket, (float4*)out, n);
}

// Round 14
// 114.341 us; speedup vs baseline: 1.3626x; 1.3626x over previous
//
#include <hip/hip_runtime.h>
#include <hip/hip_bf16.h>
#include <hip/hip_fp16.h>

#define CHUNK 4096       // edges per scatter block
#define BCAP 64          // bucket capacity per node (deg ~ Poisson(16))
#define BIN_CAP 6144     // pairs capacity per 256-node coarse bin (Poisson(4096), 32 sigma)

typedef _Float16 half8 __attribute__((ext_vector_type(8)));
typedef _Float16 half2v __attribute__((ext_vector_type(2)));
typedef float floatx4 __attribute__((ext_vector_type(4)));

__device__ __forceinline__ float2 h2f(int u)
{
    __half2 h = *reinterpret_cast<__half2*>(&u);
    return __half22float2(h);
}

__device__ __forceinline__ half2v as_h2(int u)
{
    union { int i; half2v h; } c; c.i = u; return c.h;
}

__device__ __forceinline__ int pack_h2(float a, float b)
{
    union { int i; half2v h; } c;
    c.h = (half2v){(_Float16)a, (_Float16)b};
    return c.i;
}

// ---------------------------------------------------------------------------
// MFMA fused GEMM layer 1: [Q|K|V|S] = X[n][64] @ W + b, per 64-node tile.
// Also performs bincur init (block 0) so init_bincur launch is removed.
//   q -> Q fp16 (pre-scaled); s -> S fp16; k,v -> KV packed [k01][k23][v01][v23]
// ---------------------------------------------------------------------------
__global__ __launch_bounds__(256) void gemm1(
    const float* __restrict__ X, int n,
    const float* __restrict__ W0, const float* __restrict__ W1,
    const float* __restrict__ W2, const float* __restrict__ W3,
    const float* __restrict__ B0, const float* __restrict__ B1,
    const float* __restrict__ B2, const float* __restrict__ B3,
    __half* __restrict__ Q, __half* __restrict__ S, __half* __restrict__ KV,
    int* __restrict__ bincur, int nbins)
{
    constexpr int HD = 64;
    constexpr int NTW = 4;
    const float qscale = 0.17677669529663687f;  // 1/sqrt(32)

    __shared__ _Float16 A_lds[64][72];
    __shared__ _Float16 B_lds[4 * HD][72];

    const int tid = threadIdx.x;
    const int n0 = blockIdx.x * 64;

    if (blockIdx.x == 0 && tid < nbins) bincur[tid] = tid * BIN_CAP;

    {
        const int row = tid >> 2;
        const int cb  = (tid & 3) * 16;
        const int gnode = n0 + row;
        if (gnode < n) {
            const float4* xg = reinterpret_cast<const float4*>(X + (size_t)gnode * 64 + cb);
#pragma unroll
            for (int t = 0; t < 4; ++t) {
                const float4 v = xg[t];
                A_lds[row][cb + 4 * t + 0] = (_Float16)v.x;
                A_lds[row][cb + 4 * t + 1] = (_Float16)v.y;
                A_lds[row][cb + 4 * t + 2] = (_Float16)v.z;
                A_lds[row][cb + 4 * t + 3] = (_Float16)v.w;
            }
        } else {
            const int4 z = {0, 0, 0, 0};
            *reinterpret_cast<int4*>(&A_lds[row][cb])     = z;
            *reinterpret_cast<int4*>(&A_lds[row][cb + 8]) = z;
        }
    }

    {
        const float* Ws[4] = {W0, W1, W2, W3};
#pragma unroll
        for (int m = 0; m < 4; ++m) {
            const float* W = Ws[m];
            for (int idx = tid; idx < 64 * HD; idx += 256) {
                const int k = idx / HD;
                const int jj = idx - k * HD;
                B_lds[m * HD + jj][k] = (_Float16)W[idx];
            }
        }
    }

    __syncthreads();

    const int w = tid >> 6;
    const int lane = tid & 63;
    const int lr = lane & 15;
    const int lk = (lane >> 4) * 8;

    half8 a[4][2];
#pragma unroll
    for (int mt = 0; mt < 4; ++mt)
#pragma unroll
        for (int ks = 0; ks < 2; ++ks)
            a[mt][ks] = *reinterpret_cast<const half8*>(&A_lds[mt * 16 + lr][ks * 32 + lk]);

    half8 b[NTW][2];
#pragma unroll
    for (int nt = 0; nt < NTW; ++nt)
#pragma unroll
        for (int ks = 0; ks < 2; ++ks)
            b[nt][ks] = *reinterpret_cast<const half8*>(&B_lds[w * HD + nt * 16 + lr][ks * 32 + lk]);

    floatx4 acc[4][NTW];
#pragma unroll
    for (int mt = 0; mt < 4; ++mt)
#pragma unroll
        for (int nt = 0; nt < NTW; ++nt)
            acc[mt][nt] = (floatx4){0.f, 0.f, 0.f, 0.f};

#pragma unroll
    for (int mt = 0; mt < 4; ++mt)
#pragma unroll
        for (int nt = 0; nt < NTW; ++nt) {
            acc[mt][nt] = __builtin_amdgcn_mfma_f32_16x16x32_f16(a[mt][0], b[nt][0], acc[mt][nt], 0, 0, 0);
            acc[mt][nt] = __builtin_amdgcn_mfma_f32_16x16x32_f16(a[mt][1], b[nt][1], acc[mt][nt], 0, 0, 0);
        }

    const float* Bv = (w == 0) ? B0 : (w == 1) ? B1 : (w == 2) ? B2 : B3;
    float bias[NTW];
#pragma unroll
    for (int nt = 0; nt < NTW; ++nt) bias[nt] = Bv[nt * 16 + lr];

#pragma unroll
    for (int mt = 0; mt < 4; ++mt) {
#pragma unroll
        for (int nt = 0; nt < NTW; ++nt) {
            const int jj = nt * 16 + lr;
#pragma unroll
            for (int r = 0; r < 4; ++r) {
                const int node = n0 + mt * 16 + (lane >> 4) * 4 + r;
                if (node < n) {
                    const float val = acc[mt][nt][r] + bias[nt];
                    if (w == 0)      Q[(size_t)node * HD + jj] = __float2half(val * qscale);
                    else if (w == 3) S[(size_t)node * HD + jj] = __float2half(val);
                    else             KV[(size_t)node * 2 * HD + (jj >> 2) * 8 + (w - 1) * 4 + (jj & 3)]
                                         = __float2half(val);
                }
            }
        }
    }
}

// ---------------------------------------------------------------------------
// Adjacency build: fixed-capacity coarse bins, block-claimed ranges.
// ---------------------------------------------------------------------------
__global__ __launch_bounds__(256) void scatter_fused(
    const int* __restrict__ src, const int* __restrict__ dst,
    int* __restrict__ bincur, int2* __restrict__ pairs,
    int e, int nbins)
{
    __shared__ int lh[256];
    __shared__ int lbase[256];
    const int b = blockIdx.x;
    const int tid = threadIdx.x;
    if (tid < 256) lh[tid] = 0;
    __syncthreads();

    const int base = b * CHUNK;
    const int end = min(base + CHUNK, e);

    for (int i = base + tid * 4; i < end; i += 1024) {
        if (i + 4 <= end) {
            const int4 d4 = *reinterpret_cast<const int4*>(dst + i);
            atomicAdd(&lh[d4.x >> 8], 1);
            atomicAdd(&lh[d4.y >> 8], 1);
            atomicAdd(&lh[d4.z >> 8], 1);
            atomicAdd(&lh[d4.w >> 8], 1);
        } else {
            for (int jj = i; jj < end; ++jj) atomicAdd(&lh[dst[jj] >> 8], 1);
        }
    }
    __syncthreads();

    int mycnt = 0;
    if (tid < nbins) {
        mycnt = lh[tid];
        if (mycnt > 0) lbase[tid] = atomicAdd(&bincur[tid], mycnt);
    }
    __syncthreads();
    if (tid < 256) lh[tid] = 0;
    __syncthreads();

    for (int i = base + tid * 4; i < end; i += 1024) {
        if (i + 4 <= end) {
            const int4 d4 = *reinterpret_cast<const int4*>(dst + i);
            const int4 s4 = *reinterpret_cast<const int4*>(src + i);
            int bin, off;
            bin = d4.x >> 8; off = atomicAdd(&lh[bin], 1); pairs[lbase[bin] + off] = make_int2(d4.x, s4.x);
            bin = d4.y >> 8; off = atomicAdd(&lh[bin], 1); pairs[lbase[bin] + off] = make_int2(d4.y, s4.y);
            bin = d4.z >> 8; off = atomicAdd(&lh[bin], 1); pairs[lbase[bin] + off] = make_int2(d4.z, s4.z);
            bin = d4.w >> 8; off = atomicAdd(&lh[bin], 1); pairs[lbase[bin] + off] = make_int2(d4.w, s4.w);
        } else {
            for (int jj = i; jj < end; ++jj) {
                const int d = dst[jj];
                const int bin = d >> 8;
                const int off = atomicAdd(&lh[bin], 1);
                pairs[lbase[bin] + off] = make_int2(d, src[jj]);
            }
        }
    }
}

__global__ __launch_bounds__(512) void fine_bucket(
    const int2* __restrict__ pairs, const int* __restrict__ bincur,
    int* __restrict__ cnt, int* __restrict__ bucket, int n)
{
    __shared__ int cur[256];
    const int g = blockIdx.x;
    const int tid = threadIdx.x;
    const int n0 = g << 8;
    if (tid < 256) cur[tid] = 0;
    __syncthreads();

    const int e0 = g * BIN_CAP;
    const int e1 = bincur[g];
    for (int i = e0 + tid; i < e1; i += 512) {
        const int2 p = pairs[i];
        const int slot = atomicAdd(&cur[p.x - n0], 1);
        if (slot < BCAP) bucket[(size_t)p.x * BCAP + slot] = p.y;
    }
    __syncthreads();
    const int node = n0 + tid;
    if (tid < 256 && node < n) cnt[node] = cur[tid];
}

// ---------------------------------------------------------------------------
// FUSED layer-1 attention + layer-2 GEMM.
// Block = 1024 thr / 16 waves, 64 nodes. Phase 1: wave w does attention for
// nodes n0+4w..n0+4w+3 (slot=lane>>4 edge slot, j=lane&15 -> channels 4j..4j+3),
// writing relu(att+s) fp16 into the MFMA A-tile in LDS. Phase 2: the block
// computes [Q2|K2|V2|S2] = h @ W2 + b2 (32 16x16 tiles, 2 per wave).
// ---------------------------------------------------------------------------
__global__ __launch_bounds__(1024, 8) void attn1_gemm2(
    const __half* __restrict__ Q1, const __half* __restrict__ S1,
    const int4* __restrict__ KV1, const int* __restrict__ cnt,
    const int* __restrict__ bucket,
    const float* __restrict__ W0, const float* __restrict__ W1,
    const float* __restrict__ W2, const float* __restrict__ W3,
    const float* __restrict__ B0, const float* __restrict__ B1,
    const float* __restrict__ B2, const float* __restrict__ B3,
    __half* __restrict__ Q2, __half* __restrict__ S2, __half* __restrict__ KV2,
    int n)
{
    const float qscale = 0.17677669529663687f;  // 1/sqrt(32)

    __shared__ _Float16 A_lds[64][72];          // h tile (fp16, padded)
    __shared__ _Float16 B_lds[128][72];         // W2^T: [m*32+jj][k]

    const int tid = threadIdx.x;
    const int n0 = blockIdx.x * 64;
    const int w = tid >> 6;
    const int lane = tid & 63;

    // ---- stage W2^T (4 x 64x32 f32 -> fp16) ----
    {
        const float* Ws[4] = {W0, W1, W2, W3};
#pragma unroll
        for (int m = 0; m < 4; ++m) {
            const float* W = Ws[m];
            for (int idx = tid; idx < 64 * 32; idx += 1024) {
                const int k = idx >> 5;
                const int jj = idx & 31;
                B_lds[m * 32 + jj][k] = (_Float16)W[idx];
            }
        }
    }

    // ---- phase 1: attention, 4 nodes per wave ----
    const int slot = lane >> 4;
    const int j = lane & 15;

    for (int nd = 0; nd < 4; ++nd) {
        const int wid = n0 + w * 4 + nd;
        float o0 = 0.f, o1 = 0.f, o2 = 0.f, o3 = 0.f;
        if (wid < n) {
            const int2 qi = reinterpret_cast<const int2*>(Q1 + (size_t)wid * 64)[j];
            const half2v q01 = as_h2(qi.x), q23 = as_h2(qi.y);
            const int deg = min(cnt[wid], BCAP);
            const int* blist = bucket + (size_t)wid * BCAP;

            float acc0 = 0.f, acc1 = 0.f, acc2 = 0.f, acc3 = 0.f, den = 0.f;
            if (deg > 0) {
                const int nit = (deg + 3) >> 2;
                int e = slot;
                bool vc = e < deg;
                int sc = vc ? blist[e] : 0;
                int4 kv = KV1[(size_t)sc * 16 + j];

                for (int it = 1; it < nit; ++it) {
                    const int en = (it << 2) + slot;
                    const bool vn = en < deg;
                    const int sn = vn ? blist[en] : 0;
                    const int4 kvn = KV1[(size_t)sn * 16 + j];

                    float p = __builtin_amdgcn_fdot2(as_h2(kv.x), q01,
                              __builtin_amdgcn_fdot2(as_h2(kv.y), q23, 0.f, false), false);
                    p += __shfl_xor(p, 1);
                    p += __shfl_xor(p, 2);
                    p += __shfl_xor(p, 4);
                    const float ex = vc ? __expf(p) : 0.f;
                    const float2 v01 = h2f(kv.z), v23 = h2f(kv.w);
                    den += ex;
                    acc0 = fmaf(ex, v01.x, acc0);
                    acc1 = fmaf(ex, v01.y, acc1);
                    acc2 = fmaf(ex, v23.x, acc2);
                    acc3 = fmaf(ex, v23.y, acc3);
                    kv = kvn; vc = vn;
                }
                {
                    float p = __builtin_amdgcn_fdot2(as_h2(kv.x), q01,
                              __builtin_amdgcn_fdot2(as_h2(kv.y), q23, 0.f, false), false);
                    p += __shfl_xor(p, 1);
                    p += __shfl_xor(p, 2);
                    p += __shfl_xor(p, 4);
                    const float ex = vc ? __expf(p) : 0.f;
                    const float2 v01 = h2f(kv.z), v23 = h2f(kv.w);
                    den += ex;
                    acc0 = fmaf(ex, v01.x, acc0);
                    acc1 = fmaf(ex, v01.y, acc1);
                    acc2 = fmaf(ex, v23.x, acc2);
                    acc3 = fmaf(ex, v23.y, acc3);
                }
            }
            acc0 += __shfl_xor(acc0, 16); acc0 += __shfl_xor(acc0, 32);
            acc1 += __shfl_xor(acc1, 16); acc1 += __shfl_xor(acc1, 32);
            acc2 += __shfl_xor(acc2, 16); acc2 += __shfl_xor(acc2, 32);
            acc3 += __shfl_xor(acc3, 16); acc3 += __shfl_xor(acc3, 32);
            den  += __shfl_xor(den, 16);  den  += __shfl_xor(den, 32);

            const float inv = (den > 0.f) ? (1.f / den) : 0.f;
            const int2 si = reinterpret_cast<const int2*>(S1 + (size_t)wid * 64)[j];
            const float2 s01 = h2f(si.x), s23 = h2f(si.y);
            o0 = fmaxf(fmaf(acc0, inv, s01.x), 0.f);
            o1 = fmaxf(fmaf(acc1, inv, s01.y), 0.f);
            o2 = fmaxf(fmaf(acc2, inv, s23.x), 0.f);
            o3 = fmaxf(fmaf(acc3, inv, s23.y), 0.f);
        }
        if (lane < 16) {
            int2 ov = {pack_h2(o0, o1), pack_h2(o2, o3)};
            *reinterpret_cast<int2*>(&A_lds[w * 4 + nd][4 * j]) = ov;
        }
    }

    __syncthreads();

    // ---- phase 2: gemm2, 2 tiles per wave (32 tiles: [mt 0..3][ntg 0..7]) ----
    const int lr = lane & 15;
    const int lk = (lane >> 4) * 8;

#pragma unroll
    for (int tt = 0; tt < 2; ++tt) {
        const int t = w + tt * 16;
        const int mt = t >> 3;
        const int ntg = t & 7;
        const int m = ntg >> 1;
        const int nt = ntg & 1;

        const half8 af0 = *reinterpret_cast<const half8*>(&A_lds[mt * 16 + lr][lk]);
        const half8 af1 = *reinterpret_cast<const half8*>(&A_lds[mt * 16 + lr][32 + lk]);
        const half8 bf0 = *reinterpret_cast<const half8*>(&B_lds[ntg * 16 + lr][lk]);
        const half8 bf1 = *reinterpret_cast<const half8*>(&B_lds[ntg * 16 + lr][32 + lk]);

        floatx4 acc = (floatx4){0.f, 0.f, 0.f, 0.f};
        acc = __builtin_amdgcn_mfma_f32_16x16x32_f16(af0, bf0, acc, 0, 0, 0);
        acc = __builtin_amdgcn_mfma_f32_16x16x32_f16(af1, bf1, acc, 0, 0, 0);

        const float* Bv = (m == 0) ? B0 : (m == 1) ? B1 : (m == 2) ? B2 : B3;
        const int jj = nt * 16 + lr;
        const float bias = Bv[jj];

#pragma unroll
        for (int r = 0; r < 4; ++r) {
            const int node = n0 + mt * 16 + (lane >> 4) * 4 + r;
            if (node < n) {
                const float val = acc[r] + bias;
                if (m == 0)      Q2[(size_t)node * 32 + jj] = __float2half(val * qscale);
                else if (m == 3) S2[(size_t)node * 32 + jj] = __float2half(val);
                else             KV2[(size_t)node * 64 + (jj >> 2) * 8 + (m - 1) * 4 + (jj & 3)]
                                     = __float2half(val);
            }
        }
    }
}

// ---------------------------------------------------------------------------
// Attention layer 2: heads=1, d=32. One wave per node, 8 edges/iter,
// 2-deep pipeline. Output f32 (d_out).
// ---------------------------------------------------------------------------
__global__ void attn_h1(const __half* __restrict__ Qh, const __half* __restrict__ Sh,
                        const int4* __restrict__ KVi, const int* __restrict__ cnt,
                        const int* __restrict__ bucket, float4* __restrict__ outf4, int n)
{
    const int wid = (blockIdx.x * blockDim.x + threadIdx.x) >> 6;
    if (wid >= n) return;
    const int lane = threadIdx.x & 63;
    const int slot = lane >> 3;
    const int j = lane & 7;

    const int2 qi = reinterpret_cast<const int2*>(Qh + (size_t)wid * 32)[j];
    const half2v q01 = as_h2(qi.x), q23 = as_h2(qi.y);

    const int deg = min(cnt[wid], BCAP);
    const int* blist = bucket + (size_t)wid * BCAP;

    float acc0 = 0.f, acc1 = 0.f, acc2 = 0.f, acc3 = 0.f, den = 0.f;

    if (deg > 0) {
        const int nit = (deg + 7) >> 3;

        int e = slot;
        bool vc = e < deg;
        int sc = vc ? blist[e] : 0;
        int4 kv = KVi[(size_t)sc * 8 + j];

        for (int it = 1; it < nit; ++it) {
            const int en = (it << 3) + slot;
            const bool vn = en < deg;
            const int sn = vn ? blist[en] : 0;
            const int4 kvn = KVi[(size_t)sn * 8 + j];

            float p = __builtin_amdgcn_fdot2(as_h2(kv.x), q01,
                      __builtin_amdgcn_fdot2(as_h2(kv.y), q23, 0.f, false), false);
            p += __shfl_xor(p, 1);
            p += __shfl_xor(p, 2);
            p += __shfl_xor(p, 4);
            const float ex = vc ? __expf(p) : 0.f;
            const float2 v01 = h2f(kv.z), v23 = h2f(kv.w);
            den += ex;
            acc0 = fmaf(ex, v01.x, acc0);
            acc1 = fmaf(ex, v01.y, acc1);
            acc2 = fmaf(ex, v23.x, acc2);
            acc3 = fmaf(ex, v23.y, acc3);

            kv = kvn; vc = vn;
        }
        {
            float p = __builtin_amdgcn_fdot2(as_h2(kv.x), q01,
                      __builtin_amdgcn_fdot2(as_h2(kv.y), q23, 0.f, false), false);
            p += __shfl_xor(p, 1);
            p += __shfl_xor(p, 2);
            p += __shfl_xor(p, 4);
            const float ex = vc ? __expf(p) : 0.f;
            const float2 v01 = h2f(kv.z), v23 = h2f(kv.w);
            den += ex;
            acc0 = fmaf(ex, v01.x, acc0);
            acc1 = fmaf(ex, v01.y, acc1);
            acc2 = fmaf(ex, v23.x, acc2);
            acc3 = fmaf(ex, v23.y, acc3);
        }
    }

    acc0 += __shfl_xor(acc0, 8); acc0 += __shfl_xor(acc0, 16); acc0 += __shfl_xor(acc0, 32);
    acc1 += __shfl_xor(acc1, 8); acc1 += __shfl_xor(acc1, 16); acc1 += __shfl_xor(acc1, 32);
    acc2 += __shfl_xor(acc2, 8); acc2 += __shfl_xor(acc2, 16); acc2 += __shfl_xor(acc2, 32);
    acc3 += __shfl_xor(acc3, 8); acc3 += __shfl_xor(acc3, 16); acc3 += __shfl_xor(acc3, 32);
    den  += __shfl_xor(den, 8);  den  += __shfl_xor(den, 16);  den  += __shfl_xor(den, 32);

    const float inv = (den > 0.f) ? (1.f / den) : 0.f;
    const int2 si = reinterpret_cast<const int2*>(Sh + (size_t)wid * 32)[j];
    const float2 s01 = h2f(si.x), s23 = h2f(si.y);
    float4 o;
    o.x = fmaf(acc0, inv, s01.x);
    o.y = fmaf(acc1, inv, s01.y);
    o.z = fmaf(acc2, inv, s23.x);
    o.w = fmaf(acc3, inv, s23.y);
    if (lane < 8) outf4[(size_t)wid * 8 + j] = o;
}

// ---------------------------------------------------------------------------
extern "C" void kernel_launch(void* const* d_in, const int* in_sizes, int n_in,
                              void* d_out, int out_size, void* d_ws, size_t ws_size,
                              hipStream_t stream)
{
    const float* x   = (const float*)d_in[0];
    const int* ei    = (const int*)d_in[1];
    const float* Wq1 = (const float*)d_in[2];  const float* bq1 = (const float*)d_in[3];
    const float* Wk1 = (const float*)d_in[4];  const float* bk1 = (const float*)d_in[5];
    const float* Wv1 = (const float*)d_in[6];  const float* bv1 = (const float*)d_in[7];
    const float* Ws1 = (const float*)d_in[8];  const float* bs1 = (const float*)d_in[9];
    const float* Wq2 = (const float*)d_in[10]; const float* bq2 = (const float*)d_in[11];
    const float* Wk2 = (const float*)d_in[12]; const float* bk2 = (const float*)d_in[13];
    const float* Wv2 = (const float*)d_in[14]; const float* bv2 = (const float*)d_in[15];
    const float* Ws2 = (const float*)d_in[16]; const float* bs2 = (const float*)d_in[17];

    const int n = in_sizes[0] / 64;   // 50000
    const int e = in_sizes[1] / 2;    // 800000
    const int* src = ei;
    const int* dst = ei + e;

    // workspace layout (fp16 activations; layer-2 buffers NOT aliased)
    __half* q1  = (__half*)d_ws;                       // n*64
    __half* s1  = q1 + (size_t)n * 64;                 // n*64
    __half* kv1 = s1 + (size_t)n * 64;                 // n*128
    __half* q2  = kv1 + (size_t)n * 128;               // n*32
    __half* s2  = q2 + (size_t)n * 32;                 // n*32
    __half* kv2 = s2 + (size_t)n * 32;                 // n*64
    int*  cnt    = (int*)(kv2 + (size_t)n * 64);       // n
    int*  bucket = cnt + n;                            // n*BCAP
    const int nbins = (n + 255) >> 8;                  // 196
    int2* pairs  = (int2*)(bucket + (size_t)n * BCAP); // nbins*BIN_CAP int2
    int*  bincur = (int*)(pairs + (size_t)nbins * BIN_CAP);  // nbins

    float* out = (float*)d_out;
    const int nblk  = (e + CHUNK - 1) / CHUNK;         // 196
    const int nb_gemm = (n + 63) / 64;

    // ---- layer-1 GEMM (also inits bincur) ----
    gemm1<<<nb_gemm, 256, 0, stream>>>(
        x, n, Wq1, Wk1, Wv1, Ws1, bq1, bk1, bv1, bs1, q1, s1, kv1,
        bincur, nbins);

    // ---- adjacency build ----
    scatter_fused<<<nblk, 256, 0, stream>>>(src, dst, bincur, pairs, e, nbins);
    fine_bucket<<<nbins, 512, 0, stream>>>(pairs, bincur, cnt, bucket, n);

    // ---- fused layer-1 attention + layer-2 GEMM ----
    attn1_gemm2<<<nb_gemm, 1024, 0, stream>>>(
        q1, s1, (const int4*)kv1, cnt, bucket,
        Wq2, Wk2, Wv2, Ws2, bq2, bk2, bv2, bs2,
        q2, s2, kv2, n);

    // ---- layer-2 attention ----
    attn_h1<<<(n + 3) / 4, 256, 0, stream>>>(
        q2, s2, (const int4*)kv2, cnt, bucket, (float4*)out, n);
}